// Round 21
// baseline (37.621 us; speedup 1.0000x reference)
//
#include <hip/hip_runtime.h>

// IIR filter bank: B=16, T=32768, F=30, order 6 (K=7).
// R20: ROW-STREAM waves. Cross-round invariant: non-issue residual ~18us
//   regardless of compute volume (R17 vs R18) and flush shape (R18 vs
//   R19) -> attack redundancy + transaction count structurally.
//   Block = (b, f, half-row), ONE wave, NO LDS, NO barriers. Lane l owns
//   output [256l, +256) after 128 warm (redundancy 1.5x, lowest yet;
//   23.6M total steps, 4.2us/wave issue). Six 64-sample phases:
//   {register-prefetch next 16 float4 (900cy << 1664cy FMA/phase),
//    compute, store 16 back-to-back float4 = lane-private 256B burst}.
//   Store-merge gamble: R16's leak came from ~400cy gaps between a
//   line's 16B pieces; here the 4 pieces of each line issue in ~8cy.
//   Pre-commit: WRITE>100MB or dur>=24us => revert to R18, declare.

#define BB 16
#define TT 32768
#define FF 30
#define KK 7
#define ORD 6
#define LOUT 256               // output samples per lane
#define WARM 128
#define HSPAN (64 * LOUT)      // 16384 samples per block (half row)
#define NH (TT / HSPAN)        // 2 halves per row
#define BLK 64                 // one wave, no LDS

// Transposed direct-form II step: 13 FMAs, no state shifting.
__device__ __forceinline__ float iir_step(float xv, float st[ORD],
                                          const float bcf[KK],
                                          const float acf[ORD]) {
    float y = fmaf(bcf[0], xv, st[0]);
#pragma unroll
    for (int j = 0; j < ORD - 1; ++j)
        st[j] = fmaf(-acf[j], y, fmaf(bcf[j + 1], xv, st[j + 1]));
    st[ORD - 1] = fmaf(-acf[ORD - 1], y, bcf[KK - 1] * xv);
    return y;
}

__global__ __launch_bounds__(BLK, 1) void iir_row_kernel(
    const float* __restrict__ x,    // [B][T]
    const float* __restrict__ bs,   // [F][K]
    const float* __restrict__ as_,  // [F][K]
    float* __restrict__ out)        // [B][F][T]
{
    const int bid  = blockIdx.x;    // 0..959
    const int h    = bid & 1;
    const int f    = (bid >> 1) % FF;
    const int b    = bid / (2 * FF);
    const int lane = threadIdx.x;

    // Lane-uniform coefficients -> scalar broadcast.
    const float inv_a0 = 1.0f / as_[f * KK];
    float bcf[KK], acf[ORD];
#pragma unroll
    for (int j = 0; j < KK; ++j) bcf[j] = bs[f * KK + j] * inv_a0;
#pragma unroll
    for (int j = 0; j < ORD; ++j) acf[j] = as_[f * KK + 1 + j] * inv_a0;

    const float* __restrict__ xrow = x + b * TT;
    float* __restrict__ orow = out + (b * FF + f) * TT;

    // Lane window: [base, base + 384); first 128 = warm-up (discard).
    // base >= -128; negative only for h==0, lane==0 (zero-fill = exact:
    // zero input keeps zero state).
    const int base = h * HSPAN + lane * LOUT - WARM;

    float st[ORD];
#pragma unroll
    for (int j = 0; j < ORD; ++j) st[j] = 0.0f;

    // Phase-0 load (t<0 possible).
    float4 cur[16], nxt[16];
#pragma unroll
    for (int i = 0; i < 16; ++i) {
        const int t = base + 4 * i;
        float4 v = make_float4(0.f, 0.f, 0.f, 0.f);
        if (t >= 0) v = *reinterpret_cast<const float4*>(xrow + t);
        cur[i] = v;
    }

    // 6 phases x 64 samples: s=0,1 warm (discard), s=2..5 output.
#pragma unroll
    for (int s = 0; s < 6; ++s) {
        // Register-prefetch next phase: 900cy HBM/L2 latency hides under
        // this phase's ~1664cy dependent-FMA chain.
        if (s < 5) {
#pragma unroll
            for (int i = 0; i < 16; ++i) {
                const int t = base + 64 * (s + 1) + 4 * i;
                if (s == 0) {   // only phase-1 loads can touch t<0
                    float4 v = make_float4(0.f, 0.f, 0.f, 0.f);
                    if (t >= 0) v = *reinterpret_cast<const float4*>(xrow + t);
                    nxt[i] = v;
                } else {
                    nxt[i] = *reinterpret_cast<const float4*>(xrow + t);
                }
            }
        }

        // Compute 64 steps; y dead for s<2 (DCE keeps st updates only).
        float4 y[16];
#pragma unroll
        for (int i = 0; i < 16; ++i) {
            y[i].x = iir_step(cur[i].x, st, bcf, acf);
            y[i].y = iir_step(cur[i].y, st, bcf, acf);
            y[i].z = iir_step(cur[i].z, st, bcf, acf);
            y[i].w = iir_step(cur[i].w, st, bcf, acf);
        }

        // Store: 16 back-to-back float4 = this lane's 256B burst; the 4
        // 16B pieces of each 64B line issue within ~8cy -> L2 merge.
        if (s >= 2) {
            float* __restrict__ op =
                orow + h * HSPAN + lane * LOUT + 64 * (s - 2);
#pragma unroll
            for (int i = 0; i < 16; ++i)
                *reinterpret_cast<float4*>(op + 4 * i) = y[i];
        }

#pragma unroll
        for (int i = 0; i < 16; ++i) cur[i] = nxt[i];
    }
}

extern "C" void kernel_launch(void* const* d_in, const int* in_sizes, int n_in,
                              void* d_out, int out_size, void* d_ws,
                              size_t ws_size, hipStream_t stream) {
    const float* x   = (const float*)d_in[0];
    const float* bs  = (const float*)d_in[1];
    const float* as_ = (const float*)d_in[2];
    float* out = (float*)d_out;

    const int grid = BB * FF * NH;  // 960 single-wave blocks, no LDS
    hipLaunchKernelGGL(iir_row_kernel, dim3(grid), dim3(BLK), 0, stream,
                       x, bs, as_, out);
}

// Round 22
// 23.839 us; speedup vs baseline: 1.5781x; 1.5781x over previous
//
#include <hip/hip_runtime.h>

// IIR filter bank: B=16, T=32768, F=30, order 6 (K=7).
// R21 = R18 verbatim (best: 24.2us). R20's row-stream regressed (37.6us:
// <1 wave/SIMD + 64-line-per-instruction lane-strided loads AND stores).
// Final model: output-write path for the strided [B][F][T] row pattern
// plateaus ~2.5 TB/s regardless of burst shape (256B/1KB/16KB all tried);
// compute is ~90% hidden (R18: -33% steps -> -6% time); 2 waves/SIMD
// suffice; LDS-staged flush mandatory (R16 leak). This kernel sits at
// that wall: ~24us = ~5.5us exposed issue + ~19us memory-path.
//   Lane (f, cl) warms 128 steps then outputs 128 samples (2x redundancy,
//   31.5M total steps). 2048 single-wave blocks = 8/CU, one generation.
//   ly [2][30][68] = 16.3KB; two compute+flush phases, stores drain under
//   the next phase's compute.

#define BB 16
#define TT 32768
#define FF 30
#define KK 7
#define ORD 6
#define LCH 128                // output samples per lane
#define WARM 128
#define CPB 2                  // lane groups
#define TSPAN (CPB * LCH)      // 256 samples per block
#define NBC (TT / TSPAN)       // 128 block-columns
#define YSTR 68                // ly row stride (272B: 16B-aligned, 4-way max)
#define XTILE (WARM + TSPAN)   // 384 floats = 96 float4
#define BLK 64                 // ONE wave

// Transposed direct-form II step: 13 FMAs, no state shifting.
__device__ __forceinline__ float iir_step(float xv, float st[ORD],
                                          const float bcf[KK],
                                          const float acf[ORD]) {
    float y = fmaf(bcf[0], xv, st[0]);
#pragma unroll
    for (int j = 0; j < ORD - 1; ++j)
        st[j] = fmaf(-acf[j], y, fmaf(bcf[j + 1], xv, st[j + 1]));
    st[ORD - 1] = fmaf(-acf[ORD - 1], y, bcf[KK - 1] * xv);
    return y;
}

__global__ __launch_bounds__(BLK, 2) void iir_r18_kernel(
    const float* __restrict__ x,    // [B][T]
    const float* __restrict__ bs,   // [F][K]
    const float* __restrict__ as_,  // [F][K]
    float* __restrict__ out)        // [B][F][T]
{
    __shared__ __align__(16) float ly[CPB * FF * YSTR];  // 16320 B
    __shared__ __align__(16) float lx[XTILE];            //  1536 B

    const int tid = threadIdx.x;
    const int b   = blockIdx.x / NBC;
    const int bc  = blockIdx.x % NBC;
    const int bt0 = bc * TSPAN;

    const int f  = tid % FF;        // lanes 0-29: cl=0, 30-59: cl=1
    const int cl = tid / FF;
    const bool active = tid < FF * CPB;

    // Lane-uniform-per-f coefficients.
    float bcf[KK], acf[ORD];
    {
        const int fc = active ? f : 0;
        const float inv_a0 = 1.0f / as_[fc * KK];
#pragma unroll
        for (int j = 0; j < KK; ++j) bcf[j] = bs[fc * KK + j] * inv_a0;
#pragma unroll
        for (int j = 0; j < ORD; ++j) acf[j] = as_[fc * KK + 1 + j] * inv_a0;
    }

    // Cooperative x stage: [bt0-128, bt0+256) = 96 float4; zero-fill t<0
    // (zero input keeps zero state -> exact head).
    {
        const float* __restrict__ xrow = x + b * TT;
#pragma unroll
        for (int i = 0; i < 2; ++i) {
            const int p = i * BLK + tid;
            if (p < XTILE / 4) {
                const int t = bt0 - WARM + 4 * p;
                float4 v = make_float4(0.f, 0.f, 0.f, 0.f);
                if (t >= 0) v = *reinterpret_cast<const float4*>(xrow + t);
                *reinterpret_cast<float4*>(lx + 4 * p) = v;
            }
        }
    }
    __syncthreads();

    const float4* lx4 = reinterpret_cast<const float4*>(lx);
    const int g0 = 32 * cl;         // lane window start (float4 units)
    float st[ORD];
#pragma unroll
    for (int j = 0; j < ORD; ++j) st[j] = 0.0f;
    float* lyc = ly + (cl * FF + f) * YSTR;

    // Warm-up: 128 steps (discard).
    if (active) {
#pragma unroll
        for (int k = 0; k < 32; ++k) {
            const float4 v = lx4[g0 + k];
            iir_step(v.x, st, bcf, acf);
            iir_step(v.y, st, bcf, acf);
            iir_step(v.z, st, bcf, acf);
            iir_step(v.w, st, bcf, acf);
        }
    }

    float* __restrict__ obase = out + b * FF * TT + bt0;

#pragma unroll
    for (int ph = 0; ph < 2; ++ph) {
        // Output 64 samples into this (cl,f) ly row (ds_write_b128 per 4).
        if (active) {
#pragma unroll
            for (int k = 0; k < 16; ++k) {
                const float4 v = lx4[g0 + 32 + 16 * ph + k];
                float4 y;
                y.x = iir_step(v.x, st, bcf, acf);
                y.y = iir_step(v.y, st, bcf, acf);
                y.z = iir_step(v.z, st, bcf, acf);
                y.w = iir_step(v.w, st, bcf, acf);
                *reinterpret_cast<float4*>(lyc + 4 * k) = y;
            }
        }
        __syncthreads();

        // Flush phase ph: 2 cl-groups x 30 rows x 16 float4 = 960 float4,
        // 15 per lane; each instruction = 256B runs across 4 rows.
        // Stores drain async under the next phase.
#pragma unroll
        for (int i = 0; i < 15; ++i) {
            const int j  = i * BLK + tid;       // 0..959
            const int c  = j / (FF * 16);       // cl-group
            const int r  = j % (FF * 16);
            const int fr = r >> 4;
            const int k  = r & 15;
            const float4 v = *reinterpret_cast<const float4*>(
                ly + (c * FF + fr) * YSTR + 4 * k);
            *reinterpret_cast<float4*>(
                obase + fr * TT + c * LCH + ph * 64 + 4 * k) = v;
        }
        __syncthreads();   // before next phase overwrites ly
    }
}

extern "C" void kernel_launch(void* const* d_in, const int* in_sizes, int n_in,
                              void* d_out, int out_size, void* d_ws,
                              size_t ws_size, hipStream_t stream) {
    const float* x   = (const float*)d_in[0];
    const float* bs  = (const float*)d_in[1];
    const float* as_ = (const float*)d_in[2];
    float* out = (float*)d_out;

    const int grid = BB * NBC;  // 2048 single-wave blocks = 8/CU, 1 gen
    hipLaunchKernelGGL(iir_r18_kernel, dim3(grid), dim3(BLK), 0, stream,
                       x, bs, as_, out);
}